// Round 1
// baseline (3297.549 us; speedup 1.0000x reference)
//
#include <hip/hip_runtime.h>

#define IMG   256
#define NPIX  65536          // 256*256
#define PH    63             // patches per side
#define NNODE 3969           // PH*PH
#define HID   64
#define GH    128
#define BATCH 4

// ---------------------------------------------------------------------------
// Kernel 1: fused img2patch + patch @ w3  -> sup1 [B, N, 128]
// patch[b,n,k] = input[b, 4*py + k/8, 4*px + k%8], n = py*63+px
// ---------------------------------------------------------------------------
__global__ __launch_bounds__(256) void k_sup1(const float* __restrict__ in,
                                              const float* __restrict__ w3,
                                              float* __restrict__ sup1) {
    int b = blockIdx.y;
    int t = threadIdx.x;
    int g = t & 127;
    int n = blockIdx.x * 2 + (t >> 7);
    if (n >= NNODE) return;
    int py = n / PH, px = n - py * PH;
    const float* base = in + (size_t)b * NPIX + (py * 4) * IMG + px * 4;
    float acc = 0.f;
#pragma unroll
    for (int i = 0; i < 8; ++i)
#pragma unroll
        for (int j = 0; j < 8; ++j)
            acc += base[i * IMG + j] * w3[(i * 8 + j) * GH + g];
    sup1[(size_t)b * NNODE * GH + (size_t)n * GH + g] = acc;
}

// ---------------------------------------------------------------------------
// Kernel 2/4: C[b,n,g] = (relu)( sum_m adj[b,n,m] * Bm[b,m,g] + bias[g] )
// Tiled fp32 GEMM: BM=64, BN=G (128 or 64), BK=16, 256 threads, 4x(G/16) micro
// ---------------------------------------------------------------------------
template <int G, bool RELU>
__global__ __launch_bounds__(256) void k_gemm_adj(const float* __restrict__ adj,
                                                  const float* __restrict__ Bm,
                                                  const float* __restrict__ bias,
                                                  float* __restrict__ C) {
    constexpr int TN = G / 16;
    int b = blockIdx.z;
    int row0 = blockIdx.y * 64;
    int tx = threadIdx.x & 15, ty = threadIdx.x >> 4;

    __shared__ float As[16][65];
    __shared__ float Bs[16][G + 1];

    const float* A  = adj + (size_t)b * NNODE * NNODE;
    const float* Bp = Bm + (size_t)b * NNODE * G;

    float acc[4][TN];
#pragma unroll
    for (int i = 0; i < 4; ++i)
#pragma unroll
        for (int j = 0; j < TN; ++j) acc[i][j] = 0.f;

    int ka = threadIdx.x & 15;
    int ma = threadIdx.x >> 4;

    for (int k0 = 0; k0 < NNODE; k0 += 16) {
        // stage A tile (64 rows x 16 k)
#pragma unroll
        for (int i = 0; i < 4; ++i) {
            int m = ma + 16 * i;
            int row = row0 + m, kk = k0 + ka;
            As[ka][m] = (row < NNODE && kk < NNODE) ? A[(size_t)row * NNODE + kk] : 0.f;
        }
        // stage B tile (16 k x G cols)
        if (G == 128) {
            int gb = threadIdx.x & 127, kb = threadIdx.x >> 7;
#pragma unroll
            for (int i = 0; i < 8; ++i) {
                int k = kb + 2 * i, kk = k0 + k;
                Bs[k][gb] = (kk < NNODE) ? Bp[(size_t)kk * G + gb] : 0.f;
            }
        } else {
            int gb = threadIdx.x & 63, kb = threadIdx.x >> 6;
#pragma unroll
            for (int i = 0; i < 4; ++i) {
                int k = kb + 4 * i, kk = k0 + k;
                Bs[k][gb] = (kk < NNODE) ? Bp[(size_t)kk * G + gb] : 0.f;
            }
        }
        __syncthreads();
#pragma unroll
        for (int k = 0; k < 16; ++k) {
            float av[4], bv[TN];
#pragma unroll
            for (int i = 0; i < 4; ++i) av[i] = As[k][ty + 16 * i];
#pragma unroll
            for (int j = 0; j < TN; ++j) bv[j] = Bs[k][tx + 16 * j];
#pragma unroll
            for (int i = 0; i < 4; ++i)
#pragma unroll
                for (int j = 0; j < TN; ++j) acc[i][j] += av[i] * bv[j];
        }
        __syncthreads();
    }
#pragma unroll
    for (int i = 0; i < 4; ++i) {
        int row = row0 + ty + 16 * i;
        if (row < NNODE) {
#pragma unroll
            for (int j = 0; j < TN; ++j) {
                int col = tx + 16 * j;
                float v = acc[i][j] + bias[col];
                if (RELU) v = fmaxf(v, 0.f);
                C[(size_t)b * NNODE * G + (size_t)row * G + col] = v;
            }
        }
    }
}

// ---------------------------------------------------------------------------
// Kernel 3: sup2[b,n,g] = sum_k g1[b,n,k] * w4[k,g]   (K=128, G=64)
// ---------------------------------------------------------------------------
__global__ __launch_bounds__(256) void k_sup2(const float* __restrict__ g1,
                                              const float* __restrict__ w4,
                                              float* __restrict__ sup2) {
    int b = blockIdx.y, t = threadIdx.x;
    int g = t & 63;
    int n = blockIdx.x * 4 + (t >> 6);
    if (n >= NNODE) return;
    const float* row = g1 + (size_t)b * NNODE * GH + (size_t)n * GH;
    float acc = 0.f;
#pragma unroll
    for (int k = 0; k < GH; ++k) acc += row[k] * w4[k * 64 + g];
    sup2[(size_t)b * NNODE * 64 + (size_t)n * 64 + g] = acc;
}

// ---------------------------------------------------------------------------
// conv1: 1 -> 64 ch, 3x3 SAME, relu (per-image)
// ---------------------------------------------------------------------------
__global__ __launch_bounds__(256) void k_conv1(const float* __restrict__ in,
                                               const float* __restrict__ w,
                                               const float* __restrict__ bias,
                                               float* __restrict__ h1) {
    __shared__ float s[18][18];
    __shared__ float ws[576];
    int tx = threadIdx.x & 15, ty = threadIdx.x >> 4;
    int x0 = blockIdx.x * 16, y0 = blockIdx.y * 16;
    for (int idx = threadIdx.x; idx < 324; idx += 256) {
        int yy = idx / 18, xx = idx - yy * 18;
        int gy = y0 + yy - 1, gx = x0 + xx - 1;
        s[yy][xx] = (gy >= 0 && gy < IMG && gx >= 0 && gx < IMG) ? in[gy * IMG + gx] : 0.f;
    }
    for (int idx = threadIdx.x; idx < 576; idx += 256) ws[idx] = w[idx];
    __syncthreads();
    float r[9];
#pragma unroll
    for (int dy = 0; dy < 3; ++dy)
#pragma unroll
        for (int dx = 0; dx < 3; ++dx) r[dy * 3 + dx] = s[ty + dy][tx + dx];
    int outp = (y0 + ty) * IMG + x0 + tx;
#pragma unroll 4
    for (int oc = 0; oc < 64; ++oc) {
        float acc = bias[oc];
#pragma unroll
        for (int k = 0; k < 9; ++k) acc += r[k] * ws[oc * 9 + k];
        h1[oc * NPIX + outp] = fmaxf(acc, 0.f);
    }
}

// ---------------------------------------------------------------------------
// conv2: 64 -> 64 ch, 3x3 SAME, relu (per-image). 32x32 tile, 16 oc per block
// (gridDim.z = 4 oc groups). Thread: 2x2 pixels x 16 oc.
// ---------------------------------------------------------------------------
__global__ __launch_bounds__(256) void k_conv2(const float* __restrict__ h1,
                                               const float* __restrict__ w,
                                               const float* __restrict__ bias,
                                               float* __restrict__ h2) {
    __shared__ float ins[8][34][34];   // 37 KB
    __shared__ float ws[16][8][9];     // 4.6 KB
    int ocg = blockIdx.z;
    int tx = threadIdx.x & 15, ty = threadIdx.x >> 4;
    int x0 = blockIdx.x * 32, y0 = blockIdx.y * 32;

    float acc[16][4];
#pragma unroll
    for (int oc = 0; oc < 16; ++oc)
#pragma unroll
        for (int p = 0; p < 4; ++p) acc[oc][p] = 0.f;

    for (int icc = 0; icc < 8; ++icc) {
        for (int idx = threadIdx.x; idx < 8 * 34 * 34; idx += 256) {
            int ic = idx / 1156, rem = idx - ic * 1156;
            int yy = rem / 34, xx = rem - yy * 34;
            int gy = y0 + yy - 1, gx = x0 + xx - 1;
            ins[ic][yy][xx] = (gy >= 0 && gy < IMG && gx >= 0 && gx < IMG)
                                  ? h1[(icc * 8 + ic) * NPIX + gy * IMG + gx]
                                  : 0.f;
        }
        for (int idx = threadIdx.x; idx < 1152; idx += 256) {
            int oc = idx / 72, r = idx - oc * 72;
            int ic = r / 9, k = r - ic * 9;
            ws[oc][ic][k] = w[((ocg * 16 + oc) * 64 + icc * 8 + ic) * 9 + k];
        }
        __syncthreads();
#pragma unroll
        for (int ic = 0; ic < 8; ++ic) {
            float r4[4][4];
#pragma unroll
            for (int dy = 0; dy < 4; ++dy)
#pragma unroll
                for (int dx = 0; dx < 4; ++dx)
                    r4[dy][dx] = ins[ic][ty * 2 + dy][tx * 2 + dx];
#pragma unroll
            for (int oc = 0; oc < 16; ++oc) {
                float w9[9];
#pragma unroll
                for (int k = 0; k < 9; ++k) w9[k] = ws[oc][ic][k];
#pragma unroll
                for (int p = 0; p < 4; ++p) {
                    int py = p >> 1, px = p & 1;
                    float a = acc[oc][p];
#pragma unroll
                    for (int ky = 0; ky < 3; ++ky)
#pragma unroll
                        for (int kx = 0; kx < 3; ++kx)
                            a += w9[ky * 3 + kx] * r4[py + ky][px + kx];
                    acc[oc][p] = a;
                }
            }
        }
        __syncthreads();
    }
#pragma unroll
    for (int oc = 0; oc < 16; ++oc) {
        float bb = bias[ocg * 16 + oc];
#pragma unroll
        for (int p = 0; p < 4; ++p) {
            int yy = y0 + ty * 2 + (p >> 1), xx = x0 + tx * 2 + (p & 1);
            h2[(ocg * 16 + oc) * NPIX + yy * IMG + xx] = fmaxf(acc[oc][p] + bb, 0.f);
        }
    }
}

// ---------------------------------------------------------------------------
// combine: out = relu( tmp1 + conv3(h2) + gather(g2)/cnt )   (per-image)
// ---------------------------------------------------------------------------
__global__ __launch_bounds__(256) void k_combine(const float* __restrict__ in,
                                                 const float* __restrict__ proj,
                                                 const float* __restrict__ lamp,
                                                 const float* __restrict__ h2,
                                                 const float* __restrict__ wc,
                                                 const float* __restrict__ bc,
                                                 const float* __restrict__ g2,
                                                 float* __restrict__ out) {
    __shared__ float s[16][18][18];   // 20.7 KB per chunk
    __shared__ float ws[144];
    int tx = threadIdx.x & 15, ty = threadIdx.x >> 4;
    int x0 = blockIdx.x * 16, y0 = blockIdx.y * 16;
    int y = y0 + ty, x = x0 + tx;

    float acc = bc[0];
    for (int icc = 0; icc < 4; ++icc) {
        for (int idx = threadIdx.x; idx < 16 * 324; idx += 256) {
            int ic = idx / 324, rem = idx - ic * 324;
            int yy = rem / 18, xx = rem - yy * 18;
            int gy = y0 + yy - 1, gx = x0 + xx - 1;
            s[ic][yy][xx] = (gy >= 0 && gy < IMG && gx >= 0 && gx < IMG)
                                ? h2[(icc * 16 + ic) * NPIX + gy * IMG + gx]
                                : 0.f;
        }
        for (int idx = threadIdx.x; idx < 144; idx += 256) ws[idx] = wc[icc * 144 + idx];
        __syncthreads();
#pragma unroll 4
        for (int ic = 0; ic < 16; ++ic) {
#pragma unroll
            for (int ky = 0; ky < 3; ++ky)
#pragma unroll
                for (int kx = 0; kx < 3; ++kx)
                    acc += s[ic][ty + ky][tx + kx] * ws[ic * 9 + ky * 3 + kx];
        }
        __syncthreads();
    }

    // tmp1 = in + lam*(proj - in)
    float iv = in[y * IMG + x], pv = proj[y * IMG + x];
    float tmp1 = iv + lamp[0] * (pv - iv);

    // tmp3 = overlap-add gather of g2, normalized by coverage count
    int pylo = (y >= 4) ? ((y - 4) >> 2) : 0;
    int pyhi = min(62, y >> 2);
    int pxlo = (x >= 4) ? ((x - 4) >> 2) : 0;
    int pxhi = min(62, x >> 2);
    float sum = 0.f;
    int cnt = 0;
    for (int py = pylo; py <= pyhi; ++py)
        for (int px = pxlo; px <= pxhi; ++px) {
            sum += g2[(size_t)(py * PH + px) * 64 + (y - 4 * py) * 8 + (x - 4 * px)];
            ++cnt;
        }
    float tmp3 = sum / (float)cnt;

    out[y * IMG + x] = fmaxf(tmp1 + acc + tmp3, 0.f);
}

// ---------------------------------------------------------------------------
extern "C" void kernel_launch(void* const* d_in, const int* in_sizes, int n_in,
                              void* d_out, int out_size, void* d_ws, size_t ws_size,
                              hipStream_t stream) {
    const float* input = (const float*)d_in[0];
    const float* proj  = (const float*)d_in[1];
    const float* adj   = (const float*)d_in[2];
    const float* lam   = (const float*)d_in[3];
    const float* cw1   = (const float*)d_in[4];
    const float* cb1   = (const float*)d_in[5];
    const float* cw2   = (const float*)d_in[6];
    const float* cb2   = (const float*)d_in[7];
    const float* cw3   = (const float*)d_in[8];
    const float* cb3   = (const float*)d_in[9];
    const float* gw3   = (const float*)d_in[10];
    const float* gb3   = (const float*)d_in[11];
    const float* gw4   = (const float*)d_in[12];
    const float* gb4   = (const float*)d_in[13];
    float* out = (float*)d_out;

    float* ws = (float*)d_ws;
    // persistent: g2 [B,N,64]
    float* g2 = ws;                              // 1,016,064 floats
    float* scratch = ws + 1016064;
    // GCN phase (dead before conv phase starts)
    float* sup1 = scratch;                       // 2,032,128
    float* g1   = scratch + 2032128;             // 2,032,128
    float* sup2 = scratch + 4064256;             // 1,016,064
    // conv phase (per-image, reuses same scratch)
    float* h1 = scratch;                         // 4,194,304
    float* h2 = scratch + 4194304;               // 4,194,304
    // total ws use: (1016064 + 8388608) * 4 B = 37.6 MB

    dim3 blk(256);

    // GCN branch
    k_sup1<<<dim3((NNODE + 1) / 2, BATCH), blk, 0, stream>>>(input, gw3, sup1);
    k_gemm_adj<128, true><<<dim3(1, 63, BATCH), blk, 0, stream>>>(adj, sup1, gb3, g1);
    k_sup2<<<dim3((NNODE + 3) / 4, BATCH), blk, 0, stream>>>(g1, gw4, sup2);
    k_gemm_adj<64, false><<<dim3(1, 63, BATCH), blk, 0, stream>>>(adj, sup2, gb4, g2);

    // CNN branch + final combine, per image (scratch reuse)
    for (int b = 0; b < BATCH; ++b) {
        const float* inb = input + (size_t)b * NPIX;
        k_conv1<<<dim3(16, 16), blk, 0, stream>>>(inb, cw1, cb1, h1);
        k_conv2<<<dim3(8, 8, 4), blk, 0, stream>>>(h1, cw2, cb2, h2);
        k_combine<<<dim3(16, 16), blk, 0, stream>>>(
            inb, proj + (size_t)b * NPIX, lam, h2, cw3, cb3,
            g2 + (size_t)b * NNODE * 64, out + (size_t)b * NPIX);
    }
}

// Round 2
// 1036.859 us; speedup vs baseline: 3.1803x; 3.1803x over previous
//
#include <hip/hip_runtime.h>

#define IMG   256
#define NPIX  65536          // 256*256
#define PH    63             // patches per side
#define NNODE 3969           // PH*PH
#define SN    4000           // padded node stride (mult of 32, 16B-aligned rows)
#define HID   64
#define GH    128
#define BATCH 4

typedef __attribute__((ext_vector_type(8))) short short8;
typedef __attribute__((ext_vector_type(4))) float float4v;
typedef unsigned short ushort_t;

__device__ inline ushort_t f2bf(float f) {
    union { float f; unsigned u; } v; v.f = f;
    unsigned r = v.u + 0x7FFF + ((v.u >> 16) & 1);   // RNE
    return (ushort_t)(r >> 16);
}

// ---------------------------------------------------------------------------
// adj fp32 [b][N][N] -> bf16 [b][N][SN], K-pad (3969..3999) zeroed
// ---------------------------------------------------------------------------
__global__ __launch_bounds__(256) void k_cvt_adj(const float* __restrict__ adj,
                                                 ushort_t* __restrict__ adjb) {
    int n = blockIdx.x, b = blockIdx.y;
    const float* src = adj + (size_t)(b * NNODE + n) * NNODE;
    unsigned* dst = (unsigned*)(adjb + (size_t)(b * NNODE + n) * SN);
    for (int c2 = threadIdx.x; c2 < SN / 2; c2 += 256) {
        int c = c2 * 2;
        float f0 = (c < NNODE) ? src[c] : 0.f;
        float f1 = (c + 1 < NNODE) ? src[c + 1] : 0.f;
        dst[c2] = (unsigned)f2bf(f0) | ((unsigned)f2bf(f1) << 16);
    }
}

// ---------------------------------------------------------------------------
// sup1T[b][g][n] = sum_pix patch[n][pix] * w3[pix][g]   (bf16 out, n-pad zeroed)
// ---------------------------------------------------------------------------
__global__ __launch_bounds__(256) void k_sup1(const float* __restrict__ in,
                                              const float* __restrict__ w3,
                                              ushort_t* __restrict__ sup1T) {
    int b = blockIdx.z;
    int g = blockIdx.y * 8 + (threadIdx.x >> 5);
    int n = blockIdx.x * 32 + (threadIdx.x & 31);
    ushort_t* dst = sup1T + (size_t)b * GH * SN + (size_t)g * SN + n;
    if (n >= NNODE) { *dst = 0; return; }
    int py = n / PH, px = n - py * PH;
    const float* base = in + (size_t)b * NPIX + (py * 4) * IMG + px * 4;
    float acc = 0.f;
#pragma unroll
    for (int i = 0; i < 8; ++i)
#pragma unroll
        for (int j = 0; j < 8; ++j)
            acc += base[i * IMG + j] * w3[(i * 8 + j) * GH + g];
    *dst = f2bf(acc);
}

// ---------------------------------------------------------------------------
// MFMA GEMM (transposed form): C[g][n] += sum_k supT[g][k] * adj[n][k]
// Block: 128 nodes x G, K-split by blockIdx.y (chunks of 992). 256 thr, 4 waves.
// Wave tile: G=128 -> 64x64 (2x2 waves); G=64 -> 64x32 (1x4 waves).
// LDS rows stride 40 (80 B): 16B-aligned b128 frags, conflict-free.
// ---------------------------------------------------------------------------
template <int G>
__global__ __launch_bounds__(256) void k_gemm_mfma(const ushort_t* __restrict__ adjb,
                                                   const ushort_t* __restrict__ supT,
                                                   float* __restrict__ C) {
    constexpr int FN = (G == 128) ? 4 : 2;
    const int b = blockIdx.z, ks = blockIdx.y;
    const int node0 = blockIdx.x * 128;
    const int t = threadIdx.x;
    const int lane = t & 63, w = t >> 6;
    const int l15 = lane & 15, q = lane >> 4;
    const int wm0 = (G == 128) ? (w & 1) * 64 : 0;
    const int wn0 = (G == 128) ? (w >> 1) * 64 : w * 32;

    __shared__ ushort_t Als[G][40];
    __shared__ ushort_t Bls[128][40];

    const int k0c = ks * 992;
    const int kend = (ks == 3) ? NNODE : k0c + 992;
    const int kiters = (kend - k0c + 31) >> 5;

    const ushort_t* Ab = supT + (size_t)b * G * SN;
    const ushort_t* Bb = adjb + (size_t)b * NNODE * SN;
    float* Cb = C + (size_t)b * G * SN;

    float4v acc[4][FN];
#pragma unroll
    for (int i = 0; i < 4; ++i)
#pragma unroll
        for (int j = 0; j < FN; ++j)
#pragma unroll
            for (int r = 0; r < 4; ++r) acc[i][j][r] = 0.f;

    for (int kk = 0; kk < kiters; ++kk) {
        const int kbase = k0c + kk * 32;
        // stage A (supT): G x 32 bf16, 16B vector loads
#pragma unroll
        for (int i = 0; i < G / 64; ++i) {
            int idx = t + i * 256;
            int r = idx >> 2, s = idx & 3;
            *(uint4*)&Als[r][s * 8] =
                *(const uint4*)&Ab[(size_t)r * SN + kbase + s * 8];
        }
        // stage B (adj rows): 128 x 32 bf16. Rows >= NNODE read in-bounds-of-ws
        // garbage (next region) — results for those nodes are discarded below.
#pragma unroll
        for (int i = 0; i < 2; ++i) {
            int idx = t + i * 256;
            int r = idx >> 2, s = idx & 3;
            *(uint4*)&Bls[r][s * 8] =
                *(const uint4*)&Bb[(size_t)(node0 + r) * SN + kbase + s * 8];
        }
        __syncthreads();
        short8 af[4], bf[FN];
#pragma unroll
        for (int i = 0; i < 4; ++i)
            af[i] = *(const short8*)&Als[wm0 + i * 16 + l15][q * 8];
#pragma unroll
        for (int j = 0; j < FN; ++j)
            bf[j] = *(const short8*)&Bls[wn0 + j * 16 + l15][q * 8];
#pragma unroll
        for (int i = 0; i < 4; ++i)
#pragma unroll
            for (int j = 0; j < FN; ++j)
                acc[i][j] = __builtin_amdgcn_mfma_f32_16x16x32_bf16(
                    af[i], bf[j], acc[i][j], 0, 0, 0);
        __syncthreads();
    }
    // epilogue: atomic accumulate (K-split). D: col(node)=lane&15, row(g)=q*4+r
#pragma unroll
    for (int i = 0; i < 4; ++i) {
        int gg = wm0 + i * 16 + q * 4;
#pragma unroll
        for (int j = 0; j < FN; ++j) {
            int nn = node0 + wn0 + j * 16 + l15;
            if (nn < NNODE) {
#pragma unroll
                for (int r = 0; r < 4; ++r)
                    unsafeAtomicAdd(&Cb[(size_t)(gg + r) * SN + nn], acc[i][j][r]);
            }
        }
    }
}

// ---------------------------------------------------------------------------
// sup2T[b][g][n] = sum_k relu(g1T[k][n] + gb3[k]) * w4[k][g]  (bf16, pad zeroed)
// ---------------------------------------------------------------------------
__global__ __launch_bounds__(256) void k_sup2(const float* __restrict__ g1T,
                                              const float* __restrict__ gb3,
                                              const float* __restrict__ w4,
                                              ushort_t* __restrict__ sup2T) {
    int b = blockIdx.z;
    int g = blockIdx.y * 8 + (threadIdx.x >> 5);
    int n = blockIdx.x * 32 + (threadIdx.x & 31);
    const float* gb = g1T + (size_t)b * GH * SN + n;
    float acc = 0.f;
#pragma unroll 8
    for (int k = 0; k < GH; ++k) {
        float v = fmaxf(gb[(size_t)k * SN] + gb3[k], 0.f);
        acc += v * w4[k * 64 + g];
    }
    sup2T[(size_t)b * 64 * SN + (size_t)g * SN + n] = (n < NNODE) ? f2bf(acc) : 0;
}

// ---------------------------------------------------------------------------
// conv1: 1 -> 64 ch, 3x3 SAME, relu (batched over z)
// ---------------------------------------------------------------------------
__global__ __launch_bounds__(256) void k_conv1(const float* __restrict__ in,
                                               const float* __restrict__ w,
                                               const float* __restrict__ bias,
                                               float* __restrict__ h1) {
    int b = blockIdx.z;
    const float* inb = in + (size_t)b * NPIX;
    float* h1b = h1 + (size_t)b * 64 * NPIX;
    __shared__ float s[18][18];
    __shared__ float ws[576];
    int tx = threadIdx.x & 15, ty = threadIdx.x >> 4;
    int x0 = blockIdx.x * 16, y0 = blockIdx.y * 16;
    for (int idx = threadIdx.x; idx < 324; idx += 256) {
        int yy = idx / 18, xx = idx - yy * 18;
        int gy = y0 + yy - 1, gx = x0 + xx - 1;
        s[yy][xx] = (gy >= 0 && gy < IMG && gx >= 0 && gx < IMG) ? inb[gy * IMG + gx] : 0.f;
    }
    for (int idx = threadIdx.x; idx < 576; idx += 256) ws[idx] = w[idx];
    __syncthreads();
    float r[9];
#pragma unroll
    for (int dy = 0; dy < 3; ++dy)
#pragma unroll
        for (int dx = 0; dx < 3; ++dx) r[dy * 3 + dx] = s[ty + dy][tx + dx];
    int outp = (y0 + ty) * IMG + x0 + tx;
#pragma unroll 4
    for (int oc = 0; oc < 64; ++oc) {
        float acc = bias[oc];
#pragma unroll
        for (int k = 0; k < 9; ++k) acc += r[k] * ws[oc * 9 + k];
        h1b[oc * NPIX + outp] = fmaxf(acc, 0.f);
    }
}

// ---------------------------------------------------------------------------
// conv2: 64 -> 64 ch, 3x3 SAME, relu. z = b*4 + ocg
// ---------------------------------------------------------------------------
__global__ __launch_bounds__(256) void k_conv2(const float* __restrict__ h1,
                                               const float* __restrict__ w,
                                               const float* __restrict__ bias,
                                               float* __restrict__ h2) {
    int b = blockIdx.z >> 2, ocg = blockIdx.z & 3;
    const float* h1b = h1 + (size_t)b * 64 * NPIX;
    float* h2b = h2 + (size_t)b * 64 * NPIX;
    __shared__ float ins[8][34][34];
    __shared__ float ws[16][8][9];
    int tx = threadIdx.x & 15, ty = threadIdx.x >> 4;
    int x0 = blockIdx.x * 32, y0 = blockIdx.y * 32;

    float acc[16][4];
#pragma unroll
    for (int oc = 0; oc < 16; ++oc)
#pragma unroll
        for (int p = 0; p < 4; ++p) acc[oc][p] = 0.f;

    for (int icc = 0; icc < 8; ++icc) {
        for (int idx = threadIdx.x; idx < 8 * 34 * 34; idx += 256) {
            int ic = idx / 1156, rem = idx - ic * 1156;
            int yy = rem / 34, xx = rem - yy * 34;
            int gy = y0 + yy - 1, gx = x0 + xx - 1;
            ins[ic][yy][xx] = (gy >= 0 && gy < IMG && gx >= 0 && gx < IMG)
                                  ? h1b[(icc * 8 + ic) * NPIX + gy * IMG + gx]
                                  : 0.f;
        }
        for (int idx = threadIdx.x; idx < 1152; idx += 256) {
            int oc = idx / 72, r = idx - oc * 72;
            int ic = r / 9, k = r - ic * 9;
            ws[oc][ic][k] = w[((ocg * 16 + oc) * 64 + icc * 8 + ic) * 9 + k];
        }
        __syncthreads();
#pragma unroll
        for (int ic = 0; ic < 8; ++ic) {
            float r4[4][4];
#pragma unroll
            for (int dy = 0; dy < 4; ++dy)
#pragma unroll
                for (int dx = 0; dx < 4; ++dx)
                    r4[dy][dx] = ins[ic][ty * 2 + dy][tx * 2 + dx];
#pragma unroll
            for (int oc = 0; oc < 16; ++oc) {
                float w9[9];
#pragma unroll
                for (int k = 0; k < 9; ++k) w9[k] = ws[oc][ic][k];
#pragma unroll
                for (int p = 0; p < 4; ++p) {
                    int py = p >> 1, px = p & 1;
                    float a = acc[oc][p];
#pragma unroll
                    for (int ky = 0; ky < 3; ++ky)
#pragma unroll
                        for (int kx = 0; kx < 3; ++kx)
                            a += w9[ky * 3 + kx] * r4[py + ky][px + kx];
                    acc[oc][p] = a;
                }
            }
        }
        __syncthreads();
    }
#pragma unroll
    for (int oc = 0; oc < 16; ++oc) {
        float bb = bias[ocg * 16 + oc];
#pragma unroll
        for (int p = 0; p < 4; ++p) {
            int yy = y0 + ty * 2 + (p >> 1), xx = x0 + tx * 2 + (p & 1);
            h2b[(ocg * 16 + oc) * NPIX + yy * IMG + xx] = fmaxf(acc[oc][p] + bb, 0.f);
        }
    }
}

// ---------------------------------------------------------------------------
// combine: out = relu( tmp1 + conv3(h2) + gather(g2T + gb4)/cnt ), batched z=b
// ---------------------------------------------------------------------------
__global__ __launch_bounds__(256) void k_combine(const float* __restrict__ in,
                                                 const float* __restrict__ proj,
                                                 const float* __restrict__ lamp,
                                                 const float* __restrict__ h2,
                                                 const float* __restrict__ wc,
                                                 const float* __restrict__ bc,
                                                 const float* __restrict__ g2T,
                                                 const float* __restrict__ gb4,
                                                 float* __restrict__ out) {
    int b = blockIdx.z;
    const float* inb = in + (size_t)b * NPIX;
    const float* prb = proj + (size_t)b * NPIX;
    const float* h2b = h2 + (size_t)b * 64 * NPIX;
    const float* g2b = g2T + (size_t)b * 64 * SN;
    __shared__ float s[16][18][18];
    __shared__ float ws[144];
    int tx = threadIdx.x & 15, ty = threadIdx.x >> 4;
    int x0 = blockIdx.x * 16, y0 = blockIdx.y * 16;
    int y = y0 + ty, x = x0 + tx;

    float acc = bc[0];
    for (int icc = 0; icc < 4; ++icc) {
        for (int idx = threadIdx.x; idx < 16 * 324; idx += 256) {
            int ic = idx / 324, rem = idx - ic * 324;
            int yy = rem / 18, xx = rem - yy * 18;
            int gy = y0 + yy - 1, gx = x0 + xx - 1;
            s[ic][yy][xx] = (gy >= 0 && gy < IMG && gx >= 0 && gx < IMG)
                                ? h2b[(icc * 16 + ic) * NPIX + gy * IMG + gx]
                                : 0.f;
        }
        for (int idx = threadIdx.x; idx < 144; idx += 256) ws[idx] = wc[icc * 144 + idx];
        __syncthreads();
#pragma unroll 4
        for (int ic = 0; ic < 16; ++ic) {
#pragma unroll
            for (int ky = 0; ky < 3; ++ky)
#pragma unroll
                for (int kx = 0; kx < 3; ++kx)
                    acc += s[ic][ty + ky][tx + kx] * ws[ic * 9 + ky * 3 + kx];
        }
        __syncthreads();
    }

    float iv = inb[y * IMG + x], pv = prb[y * IMG + x];
    float tmp1 = iv + lamp[0] * (pv - iv);

    int pylo = (y >= 4) ? ((y - 4) >> 2) : 0;
    int pyhi = min(62, y >> 2);
    int pxlo = (x >= 4) ? ((x - 4) >> 2) : 0;
    int pxhi = min(62, x >> 2);
    float sum = 0.f;
    int cnt = 0;
    for (int py = pylo; py <= pyhi; ++py)
        for (int px = pxlo; px <= pxhi; ++px) {
            int pix = (y - 4 * py) * 8 + (x - 4 * px);
            sum += g2b[(size_t)pix * SN + (py * PH + px)] + gb4[pix];
            ++cnt;
        }
    float tmp3 = sum / (float)cnt;

    out[(size_t)b * NPIX + y * IMG + x] = fmaxf(tmp1 + acc + tmp3, 0.f);
}

// ---------------------------------------------------------------------------
extern "C" void kernel_launch(void* const* d_in, const int* in_sizes, int n_in,
                              void* d_out, int out_size, void* d_ws, size_t ws_size,
                              hipStream_t stream) {
    const float* input = (const float*)d_in[0];
    const float* proj  = (const float*)d_in[1];
    const float* adj   = (const float*)d_in[2];
    const float* lam   = (const float*)d_in[3];
    const float* cw1   = (const float*)d_in[4];
    const float* cb1   = (const float*)d_in[5];
    const float* cw2   = (const float*)d_in[6];
    const float* cb2   = (const float*)d_in[7];
    const float* cw3   = (const float*)d_in[8];
    const float* cb3   = (const float*)d_in[9];
    const float* gw3   = (const float*)d_in[10];
    const float* gb3   = (const float*)d_in[11];
    const float* gw4   = (const float*)d_in[12];
    const float* gb4   = (const float*)d_in[13];
    float* out = (float*)d_out;

    // ws layout (bytes):
    //   g2T fp32 [4][64][SN]                    @ 0          (4,096,000)
    //   pool @ 4,096,000:
    //     GCN phase: adjb bf16 [4][N][SN]       (127,008,000)
    //                sup1T bf16 [4][128][SN]    (4,096,000)   <- also OOB-row margin
    //                g1T  fp32 [4][128][SN]     (8,192,000)
    //                sup2T bf16 [4][64][SN]     (2,048,000)
    //     conv phase (reuses pool): h1 fp32 [4][64][NPIX] (67,108,864)
    //                               h2 fp32 [4][64][NPIX] (67,108,864)
    //   total ~145.4 MB
    char* base = (char*)d_ws;
    float*    g2T   = (float*)base;
    char*     pool  = base + 4096000;
    ushort_t* adjb  = (ushort_t*)pool;
    ushort_t* sup1T = (ushort_t*)(pool + 127008000);
    float*    g1T   = (float*)(pool + 127008000 + 4096000);
    ushort_t* sup2T = (ushort_t*)(pool + 127008000 + 4096000 + 8192000);
    float*    h1    = (float*)pool;
    float*    h2    = (float*)(pool + 67108864);

    dim3 blk(256);

    hipMemsetAsync(g1T, 0, 8192000, stream);
    hipMemsetAsync(g2T, 0, 4096000, stream);

    // GCN branch (bf16 MFMA)
    k_cvt_adj<<<dim3(NNODE, BATCH), blk, 0, stream>>>(adj, adjb);
    k_sup1<<<dim3(125, 16, BATCH), blk, 0, stream>>>(input, gw3, sup1T);
    k_gemm_mfma<128><<<dim3(32, 4, BATCH), blk, 0, stream>>>(adjb, sup1T, g1T);
    k_sup2<<<dim3(125, 8, BATCH), blk, 0, stream>>>(g1T, gb3, gw4, sup2T);
    k_gemm_mfma<64><<<dim3(32, 4, BATCH), blk, 0, stream>>>(adjb, sup2T, g2T);

    // CNN branch + combine (batched grids; pool reuse is safe: stream-ordered
    // after gemm2's last read of adjb)
    k_conv1<<<dim3(16, 16, BATCH), blk, 0, stream>>>(input, cw1, cb1, h1);
    k_conv2<<<dim3(8, 8, 4 * BATCH), blk, 0, stream>>>(h1, cw2, cb2, h2);
    k_combine<<<dim3(16, 16, BATCH), blk, 0, stream>>>(
        input, proj, lam, h2, cw3, cb3, g2T, gb4, out);
}

// Round 3
// 701.652 us; speedup vs baseline: 4.6997x; 1.4777x over previous
//
#include <hip/hip_runtime.h>

#define IMG   256
#define NPIX  65536          // 256*256
#define PH    63             // patches per side
#define NNODE 3969           // PH*PH
#define SN    4000           // padded node stride (mult of 32, 16B-aligned rows)
#define HID   64
#define GH    128
#define BATCH 4

typedef __attribute__((ext_vector_type(8))) short short8;
typedef __attribute__((ext_vector_type(4))) float float4v;
typedef unsigned short ushort_t;

__device__ inline ushort_t f2bf(float f) {
    union { float f; unsigned u; } v; v.f = f;
    unsigned r = v.u + 0x7FFF + ((v.u >> 16) & 1);   // RNE
    return (ushort_t)(r >> 16);
}

// ---------------------------------------------------------------------------
// adj fp32 [b][N][N] -> bf16 [b][N][SN], K-pad (3969..3999) zeroed
// ---------------------------------------------------------------------------
__global__ __launch_bounds__(256) void k_cvt_adj(const float* __restrict__ adj,
                                                 ushort_t* __restrict__ adjb) {
    int n = blockIdx.x, b = blockIdx.y;
    const float* src = adj + (size_t)(b * NNODE + n) * NNODE;
    unsigned* dst = (unsigned*)(adjb + (size_t)(b * NNODE + n) * SN);
    for (int c2 = threadIdx.x; c2 < SN / 2; c2 += 256) {
        int c = c2 * 2;
        float f0 = (c < NNODE) ? src[c] : 0.f;
        float f1 = (c + 1 < NNODE) ? src[c + 1] : 0.f;
        dst[c2] = (unsigned)f2bf(f0) | ((unsigned)f2bf(f1) << 16);
    }
}

// ---------------------------------------------------------------------------
// sup1T[b][g][n] = sum_pix patch[n][pix] * w3[pix][g]   (bf16 out, n-pad zeroed)
// ---------------------------------------------------------------------------
__global__ __launch_bounds__(256) void k_sup1(const float* __restrict__ in,
                                              const float* __restrict__ w3,
                                              ushort_t* __restrict__ sup1T) {
    int b = blockIdx.z;
    int g = blockIdx.y * 8 + (threadIdx.x >> 5);
    int n = blockIdx.x * 32 + (threadIdx.x & 31);
    ushort_t* dst = sup1T + (size_t)b * GH * SN + (size_t)g * SN + n;
    if (n >= NNODE) { *dst = 0; return; }
    int py = n / PH, px = n - py * PH;
    const float* base = in + (size_t)b * NPIX + (py * 4) * IMG + px * 4;
    float acc = 0.f;
#pragma unroll
    for (int i = 0; i < 8; ++i)
#pragma unroll
        for (int j = 0; j < 8; ++j)
            acc += base[i * IMG + j] * w3[(i * 8 + j) * GH + g];
    *dst = f2bf(acc);
}

// ---------------------------------------------------------------------------
// MFMA GEMM (transposed form): C[g][n] += sum_k supT[g][k] * adj[n][k]
// ---------------------------------------------------------------------------
template <int G>
__global__ __launch_bounds__(256) void k_gemm_mfma(const ushort_t* __restrict__ adjb,
                                                   const ushort_t* __restrict__ supT,
                                                   float* __restrict__ C) {
    constexpr int FN = (G == 128) ? 4 : 2;
    const int b = blockIdx.z, ks = blockIdx.y;
    const int node0 = blockIdx.x * 128;
    const int t = threadIdx.x;
    const int lane = t & 63, w = t >> 6;
    const int l15 = lane & 15, q = lane >> 4;
    const int wm0 = (G == 128) ? (w & 1) * 64 : 0;
    const int wn0 = (G == 128) ? (w >> 1) * 64 : w * 32;

    __shared__ ushort_t Als[G][40];
    __shared__ ushort_t Bls[128][40];

    const int k0c = ks * 992;
    const int kend = (ks == 3) ? NNODE : k0c + 992;
    const int kiters = (kend - k0c + 31) >> 5;

    const ushort_t* Ab = supT + (size_t)b * G * SN;
    const ushort_t* Bb = adjb + (size_t)b * NNODE * SN;
    float* Cb = C + (size_t)b * G * SN;

    float4v acc[4][FN];
#pragma unroll
    for (int i = 0; i < 4; ++i)
#pragma unroll
        for (int j = 0; j < FN; ++j)
#pragma unroll
            for (int r = 0; r < 4; ++r) acc[i][j][r] = 0.f;

    for (int kk = 0; kk < kiters; ++kk) {
        const int kbase = k0c + kk * 32;
#pragma unroll
        for (int i = 0; i < G / 64; ++i) {
            int idx = t + i * 256;
            int r = idx >> 2, s = idx & 3;
            *(uint4*)&Als[r][s * 8] =
                *(const uint4*)&Ab[(size_t)r * SN + kbase + s * 8];
        }
#pragma unroll
        for (int i = 0; i < 2; ++i) {
            int idx = t + i * 256;
            int r = idx >> 2, s = idx & 3;
            *(uint4*)&Bls[r][s * 8] =
                *(const uint4*)&Bb[(size_t)(node0 + r) * SN + kbase + s * 8];
        }
        __syncthreads();
        short8 af[4], bf[FN];
#pragma unroll
        for (int i = 0; i < 4; ++i)
            af[i] = *(const short8*)&Als[wm0 + i * 16 + l15][q * 8];
#pragma unroll
        for (int j = 0; j < FN; ++j)
            bf[j] = *(const short8*)&Bls[wn0 + j * 16 + l15][q * 8];
#pragma unroll
        for (int i = 0; i < 4; ++i)
#pragma unroll
            for (int j = 0; j < FN; ++j)
                acc[i][j] = __builtin_amdgcn_mfma_f32_16x16x32_bf16(
                    af[i], bf[j], acc[i][j], 0, 0, 0);
        __syncthreads();
    }
#pragma unroll
    for (int i = 0; i < 4; ++i) {
        int gg = wm0 + i * 16 + q * 4;
#pragma unroll
        for (int j = 0; j < FN; ++j) {
            int nn = node0 + wn0 + j * 16 + l15;
            if (nn < NNODE) {
#pragma unroll
                for (int r = 0; r < 4; ++r)
                    unsafeAtomicAdd(&Cb[(size_t)(gg + r) * SN + nn], acc[i][j][r]);
            }
        }
    }
}

// ---------------------------------------------------------------------------
// sup2T[b][g][n] = sum_k relu(g1T[k][n] + gb3[k]) * w4[k][g]  (bf16, pad zeroed)
// ---------------------------------------------------------------------------
__global__ __launch_bounds__(256) void k_sup2(const float* __restrict__ g1T,
                                              const float* __restrict__ gb3,
                                              const float* __restrict__ w4,
                                              ushort_t* __restrict__ sup2T) {
    int b = blockIdx.z;
    int g = blockIdx.y * 8 + (threadIdx.x >> 5);
    int n = blockIdx.x * 32 + (threadIdx.x & 31);
    const float* gb = g1T + (size_t)b * GH * SN + n;
    float acc = 0.f;
#pragma unroll 8
    for (int k = 0; k < GH; ++k) {
        float v = fmaxf(gb[(size_t)k * SN] + gb3[k], 0.f);
        acc += v * w4[k * 64 + g];
    }
    sup2T[(size_t)b * 64 * SN + (size_t)g * SN + n] = (n < NNODE) ? f2bf(acc) : 0;
}

// ---------------------------------------------------------------------------
// conv1: 1 -> 64 ch, 3x3 SAME, relu. Output NHWC bf16: h1n[b][pix][64]
// ---------------------------------------------------------------------------
__global__ __launch_bounds__(256) void k_conv1(const float* __restrict__ in,
                                               const float* __restrict__ w,
                                               const float* __restrict__ bias,
                                               ushort_t* __restrict__ h1n) {
    int b = blockIdx.z;
    const float* inb = in + (size_t)b * NPIX;
    __shared__ float s[18][18];
    __shared__ float ws[576];
    int tx = threadIdx.x & 15, ty = threadIdx.x >> 4;
    int x0 = blockIdx.x * 16, y0 = blockIdx.y * 16;
    for (int idx = threadIdx.x; idx < 324; idx += 256) {
        int yy = idx / 18, xx = idx - yy * 18;
        int gy = y0 + yy - 1, gx = x0 + xx - 1;
        s[yy][xx] = (gy >= 0 && gy < IMG && gx >= 0 && gx < IMG) ? inb[gy * IMG + gx] : 0.f;
    }
    for (int idx = threadIdx.x; idx < 576; idx += 256) ws[idx] = w[idx];
    __syncthreads();
    float r[9];
#pragma unroll
    for (int dy = 0; dy < 3; ++dy)
#pragma unroll
        for (int dx = 0; dx < 3; ++dx) r[dy * 3 + dx] = s[ty + dy][tx + dx];
    int outp = (y0 + ty) * IMG + x0 + tx;
    ushort_t* dst = h1n + ((size_t)b * NPIX + outp) * 64;
#pragma unroll
    for (int sgrp = 0; sgrp < 8; ++sgrp) {
        unsigned pk[4];
#pragma unroll
        for (int h = 0; h < 4; ++h) {
            int oc0 = sgrp * 8 + h * 2;
            float a0 = bias[oc0], a1 = bias[oc0 + 1];
#pragma unroll
            for (int k = 0; k < 9; ++k) {
                a0 += r[k] * ws[oc0 * 9 + k];
                a1 += r[k] * ws[(oc0 + 1) * 9 + k];
            }
            a0 = fmaxf(a0, 0.f); a1 = fmaxf(a1, 0.f);
            pk[h] = (unsigned)f2bf(a0) | ((unsigned)f2bf(a1) << 16);
        }
        *(uint4*)&dst[sgrp * 8] = *(uint4*)pk;
    }
}

// ---------------------------------------------------------------------------
// prepack conv2 weights: cw2 [oc][ic][3][3] fp32 -> W2p [tap][oc][ic] bf16
// ---------------------------------------------------------------------------
__global__ __launch_bounds__(256) void k_prepack(const float* __restrict__ w,
                                                 ushort_t* __restrict__ W2p) {
    int idx = blockIdx.x * 256 + threadIdx.x;   // 9*64*64 = 36864
    if (idx >= 36864) return;
    int tap = idx >> 12, rem = idx & 4095;
    int oc = rem >> 6, ic = rem & 63;
    W2p[idx] = f2bf(w[(oc * 64 + ic) * 9 + tap]);
}

// ---------------------------------------------------------------------------
// conv2 implicit-GEMM MFMA: 64oc x (32x8 pixel tile), K = 9 taps x 64 ic.
// h1 NHWC bf16 in; h2 NCHW fp32 out (+bias+relu).
// LDS: full input halo 34x10 x 64ic, ic padded to 72 (2-way max bank alias,
// 144B rows keep 16B alignment). No barriers in the K loop.
// ---------------------------------------------------------------------------
__global__ __launch_bounds__(256) void k_conv2(const ushort_t* __restrict__ h1n,
                                               const ushort_t* __restrict__ W2p,
                                               const float* __restrict__ bias,
                                               float* __restrict__ h2) {
    __shared__ ushort_t Xs[340 * 72];           // 48,960 B
    const int b = blockIdx.z;
    const ushort_t* h1b = h1n + (size_t)b * NPIX * 64;
    float* h2b = h2 + (size_t)b * 64 * NPIX;
    const int t = threadIdx.x;
    const int lane = t & 63, w = t >> 6;
    const int l15 = lane & 15, q = lane >> 4;
    const int x0 = blockIdx.x * 32, y0 = blockIdx.y * 8;

    // stage halo: 340 pixels x 64 ic bf16 (8 x 16B chunks per pixel)
    for (int idx = t; idx < 2720; idx += 256) {
        int hp = idx >> 3, s = idx & 7;
        int hy = hp / 34, hx = hp - hy * 34;
        int gy = y0 + hy - 1, gx = x0 + hx - 1;
        uint4 v = {0u, 0u, 0u, 0u};
        if (gy >= 0 && gy < IMG && gx >= 0 && gx < IMG)
            v = *(const uint4*)&h1b[((size_t)gy * IMG + gx) * 64 + s * 8];
        *(uint4*)&Xs[hp * 72 + s * 8] = v;
    }
    __syncthreads();

    const int wn0 = w * 64;                     // wave's 64-pixel strip
    int pbase[4];
#pragma unroll
    for (int j = 0; j < 4; ++j) {
        int p = wn0 + j * 16 + l15;
        pbase[j] = (p >> 5) * 34 + (p & 31);
    }

    float4v acc[4][4];
#pragma unroll
    for (int i = 0; i < 4; ++i)
#pragma unroll
        for (int j = 0; j < 4; ++j)
#pragma unroll
            for (int r = 0; r < 4; ++r) acc[i][j][r] = 0.f;

    for (int tap = 0; tap < 9; ++tap) {
        int ky = tap / 3, kx = tap - ky * 3;
        const ushort_t* wp = W2p + tap * 4096;
#pragma unroll
        for (int c = 0; c < 2; ++c) {
            short8 af[4], bf[4];
#pragma unroll
            for (int i = 0; i < 4; ++i)
                af[i] = *(const short8*)&wp[(i * 16 + l15) * 64 + c * 32 + q * 8];
#pragma unroll
            for (int j = 0; j < 4; ++j)
                bf[j] = *(const short8*)&Xs[(pbase[j] + ky * 34 + kx) * 72 + c * 32 + q * 8];
#pragma unroll
            for (int i = 0; i < 4; ++i)
#pragma unroll
                for (int j = 0; j < 4; ++j)
                    acc[i][j] = __builtin_amdgcn_mfma_f32_16x16x32_bf16(
                        af[i], bf[j], acc[i][j], 0, 0, 0);
        }
    }

    // epilogue: D col = pixel (lane&15), row = oc (q*4+r)
#pragma unroll
    for (int i = 0; i < 4; ++i) {
#pragma unroll
        for (int j = 0; j < 4; ++j) {
            int p = wn0 + j * 16 + l15;
            int y = y0 + (p >> 5), x = x0 + (p & 31);
#pragma unroll
            for (int r = 0; r < 4; ++r) {
                int oc = i * 16 + q * 4 + r;
                h2b[(size_t)oc * NPIX + (size_t)y * IMG + x] =
                    fmaxf(acc[i][j][r] + bias[oc], 0.f);
            }
        }
    }
}

// ---------------------------------------------------------------------------
// combine: out = relu( tmp1 + conv3(h2) + gather(g2T + gb4)/cnt ), batched z=b
// ---------------------------------------------------------------------------
__global__ __launch_bounds__(256) void k_combine(const float* __restrict__ in,
                                                 const float* __restrict__ proj,
                                                 const float* __restrict__ lamp,
                                                 const float* __restrict__ h2,
                                                 const float* __restrict__ wc,
                                                 const float* __restrict__ bc,
                                                 const float* __restrict__ g2T,
                                                 const float* __restrict__ gb4,
                                                 float* __restrict__ out) {
    int b = blockIdx.z;
    const float* inb = in + (size_t)b * NPIX;
    const float* prb = proj + (size_t)b * NPIX;
    const float* h2b = h2 + (size_t)b * 64 * NPIX;
    const float* g2b = g2T + (size_t)b * 64 * SN;
    __shared__ float s[16][18][18];
    __shared__ float ws[144];
    int tx = threadIdx.x & 15, ty = threadIdx.x >> 4;
    int x0 = blockIdx.x * 16, y0 = blockIdx.y * 16;
    int y = y0 + ty, x = x0 + tx;

    float acc = bc[0];
    for (int icc = 0; icc < 4; ++icc) {
        for (int idx = threadIdx.x; idx < 16 * 324; idx += 256) {
            int ic = idx / 324, rem = idx - ic * 324;
            int yy = rem / 18, xx = rem - yy * 18;
            int gy = y0 + yy - 1, gx = x0 + xx - 1;
            s[ic][yy][xx] = (gy >= 0 && gy < IMG && gx >= 0 && gx < IMG)
                                ? h2b[(icc * 16 + ic) * NPIX + gy * IMG + gx]
                                : 0.f;
        }
        for (int idx = threadIdx.x; idx < 144; idx += 256) ws[idx] = wc[icc * 144 + idx];
        __syncthreads();
#pragma unroll 4
        for (int ic = 0; ic < 16; ++ic) {
#pragma unroll
            for (int ky = 0; ky < 3; ++ky)
#pragma unroll
                for (int kx = 0; kx < 3; ++kx)
                    acc += s[ic][ty + ky][tx + kx] * ws[ic * 9 + ky * 3 + kx];
        }
        __syncthreads();
    }

    float iv = inb[y * IMG + x], pv = prb[y * IMG + x];
    float tmp1 = iv + lamp[0] * (pv - iv);

    int pylo = (y >= 4) ? ((y - 4) >> 2) : 0;
    int pyhi = min(62, y >> 2);
    int pxlo = (x >= 4) ? ((x - 4) >> 2) : 0;
    int pxhi = min(62, x >> 2);
    float sum = 0.f;
    int cnt = 0;
    for (int py = pylo; py <= pyhi; ++py)
        for (int px = pxlo; px <= pxhi; ++px) {
            int pix = (y - 4 * py) * 8 + (x - 4 * px);
            sum += g2b[(size_t)pix * SN + (py * PH + px)] + gb4[pix];
            ++cnt;
        }
    float tmp3 = sum / (float)cnt;

    out[(size_t)b * NPIX + y * IMG + x] = fmaxf(tmp1 + acc + tmp3, 0.f);
}

// ---------------------------------------------------------------------------
extern "C" void kernel_launch(void* const* d_in, const int* in_sizes, int n_in,
                              void* d_out, int out_size, void* d_ws, size_t ws_size,
                              hipStream_t stream) {
    const float* input = (const float*)d_in[0];
    const float* proj  = (const float*)d_in[1];
    const float* adj   = (const float*)d_in[2];
    const float* lam   = (const float*)d_in[3];
    const float* cw1   = (const float*)d_in[4];
    const float* cb1   = (const float*)d_in[5];
    const float* cw2   = (const float*)d_in[6];
    const float* cb2   = (const float*)d_in[7];
    const float* cw3   = (const float*)d_in[8];
    const float* cb3   = (const float*)d_in[9];
    const float* gw3   = (const float*)d_in[10];
    const float* gb3   = (const float*)d_in[11];
    const float* gw4   = (const float*)d_in[12];
    const float* gb4   = (const float*)d_in[13];
    float* out = (float*)d_out;

    // ws layout (bytes), total 145,440,000 (same as round 2):
    //   g2T fp32 [4][64][SN]                    @ 0          (4,096,000)
    //   pool @ 4,096,000:
    //     GCN phase: adjb bf16 [4][N][SN]       (127,008,000)
    //                sup1T bf16 [4][128][SN]    (4,096,000)
    //                g1T  fp32 [4][128][SN]     (8,192,000)
    //                sup2T bf16 [4][64][SN]     (2,048,000)
    //     conv phase (reuses pool, stream-ordered after gemm<64>):
    //                h1n bf16 [4][NPIX][64]     (33,554,432)
    //                h2  fp32 [4][64][NPIX]     (67,108,864)
    //                W2p bf16 [9][64][64]       (73,728)
    char* base = (char*)d_ws;
    float*    g2T   = (float*)base;
    char*     pool  = base + 4096000;
    ushort_t* adjb  = (ushort_t*)pool;
    ushort_t* sup1T = (ushort_t*)(pool + 127008000);
    float*    g1T   = (float*)(pool + 127008000 + 4096000);
    ushort_t* sup2T = (ushort_t*)(pool + 127008000 + 4096000 + 8192000);
    ushort_t* h1n   = (ushort_t*)pool;
    float*    h2    = (float*)(pool + 33554432);
    ushort_t* W2p   = (ushort_t*)(pool + 33554432 + 67108864);

    dim3 blk(256);

    hipMemsetAsync(g1T, 0, 8192000, stream);
    hipMemsetAsync(g2T, 0, 4096000, stream);

    // GCN branch (bf16 MFMA)
    k_cvt_adj<<<dim3(NNODE, BATCH), blk, 0, stream>>>(adj, adjb);
    k_sup1<<<dim3(125, 16, BATCH), blk, 0, stream>>>(input, gw3, sup1T);
    k_gemm_mfma<128><<<dim3(32, 4, BATCH), blk, 0, stream>>>(adjb, sup1T, g1T);
    k_sup2<<<dim3(125, 8, BATCH), blk, 0, stream>>>(g1T, gb3, gw4, sup2T);
    k_gemm_mfma<64><<<dim3(32, 4, BATCH), blk, 0, stream>>>(adjb, sup2T, g2T);

    // CNN branch + combine (pool reuse safe: stream-ordered after gemm<64>)
    k_prepack<<<dim3(144), blk, 0, stream>>>(cw2, W2p);
    k_conv1<<<dim3(16, 16, BATCH), blk, 0, stream>>>(input, cw1, cb1, h1n);
    k_conv2<<<dim3(8, 32, BATCH), blk, 0, stream>>>(h1n, W2p, cb2, h2);
    k_combine<<<dim3(16, 16, BATCH), blk, 0, stream>>>(
        input, proj, lam, h2, cw3, cb3, g2T, gb4, out);
}